// Round 4
// baseline (1085.062 us; speedup 1.0000x reference)
//
#include <hip/hip_runtime.h>

typedef __attribute__((ext_vector_type(8))) short bf16x8;
typedef __attribute__((ext_vector_type(4))) float f32x4;

__device__ __forceinline__ unsigned short f2bf(float f) {  // RNE
  unsigned u = __float_as_uint(f);
  u += 0x7FFFu + ((u >> 16) & 1u);
  return (unsigned short)(u >> 16);
}
__device__ __forceinline__ float bflo(unsigned u) { return __uint_as_float(u << 16); }
__device__ __forceinline__ float bfhi(unsigned u) { return __uint_as_float(u & 0xFFFF0000u); }

// ---------------- MFMA bf16 GEMM body (m89/m91-verified layouts) ----------------
template <int CO, bool AF32>
__device__ __forceinline__ void gemm_body(const void* __restrict__ Aptr,
                                          const float* __restrict__ W,
                                          unsigned short* __restrict__ Y, int N,
                                          int bid, int tid, unsigned short* Wl) {
  constexpr int K = 128;
  constexpr int SP = K + 8;  // padded LDS row stride (shorts)
  for (int i = tid; i < K * CO; i += 256) {
    int k = i / CO, n = i % CO;
    Wl[n * SP + k] = f2bf(W[i]);
  }
  __syncthreads();

  const int lane = tid & 63;
  const int quad = lane >> 4, l16 = lane & 15;
  const int mbase = bid * 64 + (tid >> 6) * 16;
  const int arow = min(mbase + l16, N - 1);

  bf16x8 afrag[4];
  if constexpr (AF32) {
    const float* A = (const float*)Aptr + (size_t)arow * K;
#pragma unroll
    for (int ks = 0; ks < 4; ks++) {
      const float4* p = (const float4*)(A + ks * 32 + quad * 8);
      float4 f0 = p[0], f1 = p[1];
      afrag[ks] = (bf16x8){(short)f2bf(f0.x), (short)f2bf(f0.y), (short)f2bf(f0.z), (short)f2bf(f0.w),
                           (short)f2bf(f1.x), (short)f2bf(f1.y), (short)f2bf(f1.z), (short)f2bf(f1.w)};
    }
  } else {
    const unsigned short* A = (const unsigned short*)Aptr + (size_t)arow * K;
#pragma unroll
    for (int ks = 0; ks < 4; ks++) afrag[ks] = *(const bf16x8*)(A + ks * 32 + quad * 8);
  }

#pragma unroll
  for (int ct = 0; ct < CO / 16; ct++) {
    f32x4 acc = {0.0f, 0.0f, 0.0f, 0.0f};
#pragma unroll
    for (int ks = 0; ks < 4; ks++) {
      bf16x8 b = *(const bf16x8*)(&Wl[(ct * 16 + l16) * SP + ks * 32 + quad * 8]);
      acc = __builtin_amdgcn_mfma_f32_16x16x32_bf16(afrag[ks], b, acc, 0, 0, 0);
    }
#pragma unroll
    for (int reg = 0; reg < 4; reg++) {
      int node = mbase + quad * 4 + reg;
      if (node < N) Y[(size_t)node * CO + ct * 16 + l16] = f2bf(acc[reg]);
    }
  }
}

// ---------------- mega1: GEMM1 | edge histogram+rank capture | batch boundaries ----
__global__ __launch_bounds__(256) void k_mega1(const float* __restrict__ x,
                                               const float* __restrict__ W1,
                                               unsigned short* __restrict__ xw1b, int N,
                                               const int* __restrict__ dst,
                                               int* __restrict__ cnt,
                                               int* __restrict__ rank, int E,
                                               const int* __restrict__ batch,
                                               int* __restrict__ firstIdx,
                                               int gM, int gE4) {
  __shared__ unsigned short Wl[128 * 136];
  const int bid = blockIdx.x, tid = threadIdx.x;
  if (bid < gM) {
    gemm_body<128, true>(x, W1, xw1b, N, bid, tid, Wl);
  } else if (bid < gM + gE4) {
    int e0 = (bid - gM) * 1024 + tid * 4;
    if (e0 + 3 < E) {
      int4 d4 = *(const int4*)(dst + e0);
      int4 r;
      r.x = atomicAdd(&cnt[d4.x], 1);
      r.y = atomicAdd(&cnt[d4.y], 1);
      r.z = atomicAdd(&cnt[d4.z], 1);
      r.w = atomicAdd(&cnt[d4.w], 1);
      *(int4*)(rank + e0) = r;
    } else {
      for (int e = e0; e < E; e++) rank[e] = atomicAdd(&cnt[dst[e]], 1);
    }
  } else {
    int n = (bid - gM - gE4) * 256 + tid;
    if (n < N) {
      int b = batch[n];
      if (n == 0 || batch[n - 1] != b) firstIdx[b] = n + 1;  // first occurrence, +1-encoded
    }
  }
}

// ---------------- segment allocation (order-free prefix) ----------------
__global__ void k_seg(const int* __restrict__ cnt, int* __restrict__ start,
                      float* __restrict__ dinv, int* __restrict__ counter, int N) {
  const int v = blockIdx.x * 256 + threadIdx.x;
  const int lane = threadIdx.x & 63;
  int c = (v < N) ? cnt[v] : 0;
  int incl = c;
#pragma unroll
  for (int d = 1; d < 64; d <<= 1) {
    int t = __shfl_up(incl, d, 64);
    if (lane >= d) incl += t;
  }
  int base = 0;
  if (lane == 63) base = atomicAdd(counter, incl);
  base = __shfl(base, 63, 64);
  if (v < N) {
    start[v] = base + incl - c;
    dinv[v] = rsqrtf((float)(c + 1));  // +1 self-loop
  }
}

// atomic-free fill: position = start[dst] + rank[e]
__global__ void k_fill(const int* __restrict__ src, const int* __restrict__ dst,
                       const int* __restrict__ rank, const int* __restrict__ start,
                       const float* __restrict__ dinv, int2* __restrict__ colw, int E) {
  int e = blockIdx.x * 256 + threadIdx.x;
  if (e < E) {
    int s = src[e], d = dst[e];
    int p = start[d] + rank[e];
    float w = dinv[s] * dinv[d];
    colw[p] = make_int2(s, __float_as_int(w));
  }
}

// ---------------- layer-1 aggregate: 16 lanes/edge, 4 loads in flight ----------------
__global__ __launch_bounds__(256) void k_agg128(const unsigned short* __restrict__ xwb,
                                                const float* __restrict__ dinv,
                                                const int* __restrict__ start,
                                                const int* __restrict__ cnt,
                                                const int2* __restrict__ colw,
                                                const float* __restrict__ bias,
                                                unsigned short* __restrict__ out, int N) {
  __shared__ int2 sEdge[4][64];
  const int tid = threadIdx.x;
  const int lane = tid & 63;
  const int wv = tid >> 6;
  const int slot = lane >> 4;  // 4 edges per round
  const int fl = lane & 15;    // 16B feature group within 256B row
  const int v = blockIdx.x * 4 + wv;
  if (v >= N) return;

  float acc[8] = {0.f, 0.f, 0.f, 0.f, 0.f, 0.f, 0.f, 0.f};
  const float dv = dinv[v];
  const float d2 = dv * dv;
  if (slot == 0) {
    uint4 s = *(const uint4*)((const char*)xwb + (((size_t)v << 8) | (fl << 4)));
    acc[0] += d2 * bflo(s.x); acc[1] += d2 * bfhi(s.x);
    acc[2] += d2 * bflo(s.y); acc[3] += d2 * bfhi(s.y);
    acc[4] += d2 * bflo(s.z); acc[5] += d2 * bfhi(s.z);
    acc[6] += d2 * bflo(s.w); acc[7] += d2 * bfhi(s.w);
  }

  const int j0 = start[v], jc = cnt[v];
  for (int base = 0; base < jc; base += 64) {
    int2 cw = (base + lane < jc) ? colw[j0 + base + lane] : make_int2(0, 0);
    sEdge[wv][lane] = cw;  // per-wave region, same-wave readback (no barrier)
    int m = jc - base;
    if (m > 64) m = 64;
    const int rounds = (m + 3) >> 2;
    const int rp = (rounds + 3) & ~3;  // pad to x4; pad slots are (0,0)
    for (int t = 0; t < rp; t += 4) {
      uint4 rbuf[4];
      float wbuf[4];
#pragma unroll
      for (int r = 0; r < 4; r++) {
        int2 e = sEdge[wv][(t + r) * 4 + slot];
        wbuf[r] = __int_as_float(e.y);
        rbuf[r] = *(const uint4*)((const char*)xwb + (((unsigned)e.x << 8) | (fl << 4)));
      }
#pragma unroll
      for (int r = 0; r < 4; r++) {
        const float w = wbuf[r];
        const uint4 rr = rbuf[r];
        acc[0] += w * bflo(rr.x); acc[1] += w * bfhi(rr.x);
        acc[2] += w * bflo(rr.y); acc[3] += w * bfhi(rr.y);
        acc[4] += w * bflo(rr.z); acc[5] += w * bfhi(rr.z);
        acc[6] += w * bflo(rr.w); acc[7] += w * bfhi(rr.w);
      }
    }
  }

#pragma unroll
  for (int d = 16; d < 64; d <<= 1)
#pragma unroll
    for (int k = 0; k < 8; k++) acc[k] += __shfl_xor(acc[k], d, 64);

  if (slot == 0) {
    float4 b0 = ((const float4*)bias)[fl * 2];
    float4 b1 = ((const float4*)bias)[fl * 2 + 1];
    float a0 = fmaxf(acc[0] + b0.x, 0.f), a1 = fmaxf(acc[1] + b0.y, 0.f);
    float a2 = fmaxf(acc[2] + b0.z, 0.f), a3 = fmaxf(acc[3] + b0.w, 0.f);
    float a4 = fmaxf(acc[4] + b1.x, 0.f), a5 = fmaxf(acc[5] + b1.y, 0.f);
    float a6 = fmaxf(acc[6] + b1.z, 0.f), a7 = fmaxf(acc[7] + b1.w, 0.f);
    uint4 st;
    st.x = (unsigned)f2bf(a0) | ((unsigned)f2bf(a1) << 16);
    st.y = (unsigned)f2bf(a2) | ((unsigned)f2bf(a3) << 16);
    st.z = (unsigned)f2bf(a4) | ((unsigned)f2bf(a5) << 16);
    st.w = (unsigned)f2bf(a6) | ((unsigned)f2bf(a7) << 16);
    *(uint4*)((char*)out + (((size_t)v << 8) | (fl << 4))) = st;
  }
}

// standalone GEMM2 (h1b bf16 -> xw2b bf16)
__global__ __launch_bounds__(256) void k_gemm2(const unsigned short* __restrict__ A,
                                               const float* __restrict__ W,
                                               unsigned short* __restrict__ Y, int N) {
  __shared__ unsigned short Wl[64 * 136];
  gemm_body<64, false>(A, W, Y, N, blockIdx.x, threadIdx.x, Wl);
}

// ---------------- layer-2 aggregate + mean-pool + fused finalization ----------------
__global__ __launch_bounds__(256) void k_aggpool(const unsigned short* __restrict__ xwb,
                                                 const float* __restrict__ dinv,
                                                 const int* __restrict__ start,
                                                 const int* __restrict__ cnt,
                                                 const int2* __restrict__ colw,
                                                 const int* __restrict__ batch,
                                                 float* __restrict__ stage, int N,
                                                 int* __restrict__ done,
                                                 const int* __restrict__ firstIdx,
                                                 const float* __restrict__ b2,
                                                 float* __restrict__ out) {
  __shared__ int2 sEdge[4][64];
  __shared__ float sAcc[4][64];
  __shared__ int isLast;
  const int tid = threadIdx.x;
  const int lane = tid & 63;
  const int wv = tid >> 6;
  const int slot = lane >> 3;  // 8 edges per round
  const int fl = lane & 7;     // 16B feature group within 128B row
  const int v = blockIdx.x * 4 + wv;

  float acc[8] = {0.f, 0.f, 0.f, 0.f, 0.f, 0.f, 0.f, 0.f};
  int b = 0;
  if (v < N) {
    b = batch[v];
    const float dv = dinv[v];
    const float d2 = dv * dv;
    if (slot == 0) {
      uint4 s = *(const uint4*)((const char*)xwb + (((size_t)v << 7) | (fl << 4)));
      acc[0] += d2 * bflo(s.x); acc[1] += d2 * bfhi(s.x);
      acc[2] += d2 * bflo(s.y); acc[3] += d2 * bfhi(s.y);
      acc[4] += d2 * bflo(s.z); acc[5] += d2 * bfhi(s.z);
      acc[6] += d2 * bflo(s.w); acc[7] += d2 * bfhi(s.w);
    }
    const int j0 = start[v], jc = cnt[v];
    for (int base = 0; base < jc; base += 64) {
      int2 cw = (base + lane < jc) ? colw[j0 + base + lane] : make_int2(0, 0);
      sEdge[wv][lane] = cw;
      int m = jc - base;
      if (m > 64) m = 64;
      const int rounds = (m + 7) >> 3;       // 1..8
      const int rp = (rounds + 3) & ~3;      // pad to x4
      for (int t = 0; t < rp; t += 4) {
        uint4 rbuf[4];
        float wbuf[4];
#pragma unroll
        for (int r = 0; r < 4; r++) {
          int2 e = sEdge[wv][(t + r) * 8 + slot];
          wbuf[r] = __int_as_float(e.y);
          rbuf[r] = *(const uint4*)((const char*)xwb + (((unsigned)e.x << 7) | (fl << 4)));
        }
#pragma unroll
        for (int r = 0; r < 4; r++) {
          const float w = wbuf[r];
          const uint4 rr = rbuf[r];
          acc[0] += w * bflo(rr.x); acc[1] += w * bfhi(rr.x);
          acc[2] += w * bflo(rr.y); acc[3] += w * bfhi(rr.y);
          acc[4] += w * bflo(rr.z); acc[5] += w * bfhi(rr.z);
          acc[6] += w * bflo(rr.w); acc[7] += w * bfhi(rr.w);
        }
      }
    }
#pragma unroll
    for (int d = 8; d < 64; d <<= 1)
#pragma unroll
      for (int k = 0; k < 8; k++) acc[k] += __shfl_xor(acc[k], d, 64);
  }

  if (slot == 0) {
    *(float4*)&sAcc[wv][fl * 8] = make_float4(acc[0], acc[1], acc[2], acc[3]);
    *(float4*)&sAcc[wv][fl * 8 + 4] = make_float4(acc[4], acc[5], acc[6], acc[7]);
  }
  __syncthreads();

  const int v0 = blockIdx.x * 4;
  const int b0 = batch[min(v0, N - 1)];
  const int b3 = batch[min(v0 + 3, N - 1)];
  if ((b0 == b3) && (v0 + 3 < N)) {  // sorted batch -> block-uniform graph
    if (wv == 0) {
      float t = sAcc[0][lane] + sAcc[1][lane] + sAcc[2][lane] + sAcc[3][lane];
      atomicAdd(&stage[b0 * 64 + lane], t);
    }
  } else if (v < N) {
    atomicAdd(&stage[b * 64 + lane], sAcc[wv][lane]);
  }

  // ---- last finishing block runs the finalization (divide + bias) ----
  __threadfence();
  if (tid == 0) isLast = (atomicAdd(done, 1) == (int)gridDim.x - 1);
  __syncthreads();
  if (isLast) {
    __shared__ float denom[64];
    if (tid < 64) {
      int raw = firstIdx[tid];
      int fi = (raw > 0) ? raw - 1 : 0x7FFFFFFF;
      int m = fi;
#pragma unroll
      for (int d = 1; d < 64; d <<= 1) {
        int t = __shfl_down(m, d, 64);
        if (tid + d < 64) m = min(m, t);
      }
      int nxtm = __shfl_down(m, 1, 64);          // min first over graphs > tid
      int nxt = (tid == 63) ? N : min(nxtm, N);
      int c = (fi == 0x7FFFFFFF) ? 0 : (nxt - fi);
      denom[tid] = fmaxf((float)c, 1.0f);
    }
    __syncthreads();
    for (int i = tid; i < 64 * 64; i += 256) {
      float sv = atomicAdd(&stage[i], 0.0f);  // coherent read across XCDs
      out[i] = sv / denom[i >> 6] + b2[i & 63];
    }
  }
}

// ---------------- launch ----------------

extern "C" void kernel_launch(void* const* d_in, const int* in_sizes, int n_in,
                              void* d_out, int out_size, void* d_ws, size_t ws_size,
                              hipStream_t stream) {
  const float* x     = (const float*)d_in[0];
  const int*   ei    = (const int*)d_in[1];
  const int*   batch = (const int*)d_in[2];
  const float* W1    = (const float*)d_in[3];
  const float* b1    = (const float*)d_in[4];
  const float* W2    = (const float*)d_in[5];
  const float* b2    = (const float*)d_in[6];

  const int N = in_sizes[2];       // 50000
  const int E = in_sizes[1] / 2;   // 800000
  const int* src  = ei;
  const int* dstv = ei + E;

  // workspace layout
  unsigned short* xw1b = (unsigned short*)d_ws;      // N*128 bf16 (xw2b overlays later)
  unsigned short* h1b  = xw1b + (size_t)N * 128;     // N*128 bf16
  unsigned short* xw2b = xw1b;                       // N*64 bf16
  // zero region (single memset): cnt[N], counter[1], firstIdx[64], stage[4096], done[1]
  int*   cnt     = (int*)(h1b + (size_t)N * 128);
  int*   counter = cnt + N;
  int*   firstIdx= counter + 1;
  float* stage   = (float*)(firstIdx + 64);          // 64*64
  int*   done    = (int*)(stage + 4096);
  // non-zeroed scratch
  int*   startv  = done + 1;                         // N
  float* dinv    = (float*)(startv + N);             // N
  int2*  colw    = (int2*)(((uintptr_t)(dinv + N) + 15) & ~(uintptr_t)15);  // E pairs
  int*   rank    = (int*)(colw + E);                 // E (16B-aligned)
  float* outp    = (float*)d_out;                    // 64*64

  hipMemsetAsync(cnt, 0, (size_t)(N + 1 + 64 + 4096 + 1) * sizeof(int), stream);

  const int gM  = (N + 63) / 64;      // 782
  const int gE4 = (E + 1023) / 1024;  // 782  (4 edges/thread histogram)
  const int gE  = (E + 255) / 256;    // 3125
  const int gN  = (N + 255) / 256;    // 196
  const int gA  = (N + 3) / 4;        // 12500

  // GEMM1 + histogram/rank + batch boundaries in one launch (independent work)
  k_mega1<<<gM + gE4 + gN, 256, 0, stream>>>(x, W1, xw1b, N, dstv, cnt, rank, E,
                                             batch, firstIdx, gM, gE4);
  k_seg<<<gN, 256, 0, stream>>>(cnt, startv, dinv, counter, N);
  k_fill<<<gE, 256, 0, stream>>>(src, dstv, rank, startv, dinv, colw, E);

  // layer 1 aggregate (+bias+relu)
  k_agg128<<<gA, 256, 0, stream>>>(xw1b, dinv, startv, cnt, colw, b1, h1b, N);

  // layer 2: GEMM then aggregate fused with pooling + finalization
  k_gemm2<<<gM, 256, 0, stream>>>(h1b, W2, xw2b, N);
  k_aggpool<<<gA, 256, 0, stream>>>(xw2b, dinv, startv, cnt, colw, batch, stage, N,
                                    done, firstIdx, b2, outp);
}

// Round 5
// 233.008 us; speedup vs baseline: 4.6568x; 4.6568x over previous
//
#include <hip/hip_runtime.h>

typedef __attribute__((ext_vector_type(8))) short bf16x8;
typedef __attribute__((ext_vector_type(4))) float f32x4;

__device__ __forceinline__ unsigned short f2bf(float f) {  // RNE
  unsigned u = __float_as_uint(f);
  u += 0x7FFFu + ((u >> 16) & 1u);
  return (unsigned short)(u >> 16);
}
__device__ __forceinline__ float bflo(unsigned u) { return __uint_as_float(u << 16); }
__device__ __forceinline__ float bfhi(unsigned u) { return __uint_as_float(u & 0xFFFF0000u); }

// ---------------- MFMA bf16 GEMM body (m89/m91-verified layouts) ----------------
template <int CO, bool AF32>
__device__ __forceinline__ void gemm_body(const void* __restrict__ Aptr,
                                          const float* __restrict__ W,
                                          unsigned short* __restrict__ Y, int N,
                                          int bid, int tid, unsigned short* Wl) {
  constexpr int K = 128;
  constexpr int SP = K + 8;  // padded LDS row stride (shorts)
  for (int i = tid; i < K * CO; i += 256) {
    int k = i / CO, n = i % CO;
    Wl[n * SP + k] = f2bf(W[i]);
  }
  __syncthreads();

  const int lane = tid & 63;
  const int quad = lane >> 4, l16 = lane & 15;
  const int mbase = bid * 64 + (tid >> 6) * 16;
  const int arow = min(mbase + l16, N - 1);

  bf16x8 afrag[4];
  if constexpr (AF32) {
    const float* A = (const float*)Aptr + (size_t)arow * K;
#pragma unroll
    for (int ks = 0; ks < 4; ks++) {
      const float4* p = (const float4*)(A + ks * 32 + quad * 8);
      float4 f0 = p[0], f1 = p[1];
      afrag[ks] = (bf16x8){(short)f2bf(f0.x), (short)f2bf(f0.y), (short)f2bf(f0.z), (short)f2bf(f0.w),
                           (short)f2bf(f1.x), (short)f2bf(f1.y), (short)f2bf(f1.z), (short)f2bf(f1.w)};
    }
  } else {
    const unsigned short* A = (const unsigned short*)Aptr + (size_t)arow * K;
#pragma unroll
    for (int ks = 0; ks < 4; ks++) afrag[ks] = *(const bf16x8*)(A + ks * 32 + quad * 8);
  }

#pragma unroll
  for (int ct = 0; ct < CO / 16; ct++) {
    f32x4 acc = {0.0f, 0.0f, 0.0f, 0.0f};
#pragma unroll
    for (int ks = 0; ks < 4; ks++) {
      bf16x8 b = *(const bf16x8*)(&Wl[(ct * 16 + l16) * SP + ks * 32 + quad * 8]);
      acc = __builtin_amdgcn_mfma_f32_16x16x32_bf16(afrag[ks], b, acc, 0, 0, 0);
    }
#pragma unroll
    for (int reg = 0; reg < 4; reg++) {
      int node = mbase + quad * 4 + reg;
      if (node < N) Y[(size_t)node * CO + ct * 16 + l16] = f2bf(acc[reg]);
    }
  }
}

// ---------------- mega1: GEMM1 | edge histogram+rank capture | batch boundaries ----
__global__ __launch_bounds__(256) void k_mega1(const float* __restrict__ x,
                                               const float* __restrict__ W1,
                                               unsigned short* __restrict__ xw1b, int N,
                                               const int* __restrict__ dst,
                                               int* __restrict__ cnt,
                                               int* __restrict__ rank, int E,
                                               const int* __restrict__ batch,
                                               int* __restrict__ firstIdx,
                                               int gM, int gE4) {
  __shared__ unsigned short Wl[128 * 136];
  const int bid = blockIdx.x, tid = threadIdx.x;
  if (bid < gM) {
    gemm_body<128, true>(x, W1, xw1b, N, bid, tid, Wl);
  } else if (bid < gM + gE4) {
    int e0 = (bid - gM) * 1024 + tid * 4;
    if (e0 + 3 < E) {
      int4 d4 = *(const int4*)(dst + e0);
      int4 r;
      r.x = atomicAdd(&cnt[d4.x], 1);
      r.y = atomicAdd(&cnt[d4.y], 1);
      r.z = atomicAdd(&cnt[d4.z], 1);
      r.w = atomicAdd(&cnt[d4.w], 1);
      *(int4*)(rank + e0) = r;
    } else {
      for (int e = e0; e < E; e++) rank[e] = atomicAdd(&cnt[dst[e]], 1);
    }
  } else {
    int n = (bid - gM - gE4) * 256 + tid;
    if (n < N) {
      int b = batch[n];
      if (n == 0 || batch[n - 1] != b) firstIdx[b] = n + 1;  // first occurrence, +1-encoded
    }
  }
}

// ---------------- segment allocation (order-free prefix) ----------------
__global__ void k_seg(const int* __restrict__ cnt, int* __restrict__ start,
                      float* __restrict__ dinv, int* __restrict__ counter, int N) {
  const int v = blockIdx.x * 256 + threadIdx.x;
  const int lane = threadIdx.x & 63;
  int c = (v < N) ? cnt[v] : 0;
  int incl = c;
#pragma unroll
  for (int d = 1; d < 64; d <<= 1) {
    int t = __shfl_up(incl, d, 64);
    if (lane >= d) incl += t;
  }
  int base = 0;
  if (lane == 63) base = atomicAdd(counter, incl);
  base = __shfl(base, 63, 64);
  if (v < N) {
    start[v] = base + incl - c;
    dinv[v] = rsqrtf((float)(c + 1));  // +1 self-loop
  }
}

// atomic-free fill: position = start[dst] + rank[e]
__global__ void k_fill(const int* __restrict__ src, const int* __restrict__ dst,
                       const int* __restrict__ rank, const int* __restrict__ start,
                       const float* __restrict__ dinv, int2* __restrict__ colw, int E) {
  int e = blockIdx.x * 256 + threadIdx.x;
  if (e < E) {
    int s = src[e], d = dst[e];
    int p = start[d] + rank[e];
    float w = dinv[s] * dinv[d];
    colw[p] = make_int2(s, __float_as_int(w));
  }
}

// ---------------- layer-1 aggregate: 16 lanes/edge, 4 loads in flight ----------------
__global__ __launch_bounds__(256) void k_agg128(const unsigned short* __restrict__ xwb,
                                                const float* __restrict__ dinv,
                                                const int* __restrict__ start,
                                                const int* __restrict__ cnt,
                                                const int2* __restrict__ colw,
                                                const float* __restrict__ bias,
                                                unsigned short* __restrict__ out, int N) {
  __shared__ int2 sEdge[4][64];
  const int tid = threadIdx.x;
  const int lane = tid & 63;
  const int wv = tid >> 6;
  const int slot = lane >> 4;  // 4 edges per round
  const int fl = lane & 15;    // 16B feature group within 256B row
  const int v = blockIdx.x * 4 + wv;
  if (v >= N) return;

  float acc[8] = {0.f, 0.f, 0.f, 0.f, 0.f, 0.f, 0.f, 0.f};
  const float dv = dinv[v];
  const float d2 = dv * dv;
  if (slot == 0) {
    uint4 s = *(const uint4*)((const char*)xwb + (((size_t)v << 8) | (fl << 4)));
    acc[0] += d2 * bflo(s.x); acc[1] += d2 * bfhi(s.x);
    acc[2] += d2 * bflo(s.y); acc[3] += d2 * bfhi(s.y);
    acc[4] += d2 * bflo(s.z); acc[5] += d2 * bfhi(s.z);
    acc[6] += d2 * bflo(s.w); acc[7] += d2 * bfhi(s.w);
  }

  const int j0 = start[v], jc = cnt[v];
  for (int base = 0; base < jc; base += 64) {
    int2 cw = (base + lane < jc) ? colw[j0 + base + lane] : make_int2(0, 0);
    sEdge[wv][lane] = cw;  // per-wave region, same-wave readback (no barrier)
    int m = jc - base;
    if (m > 64) m = 64;
    const int rounds = (m + 3) >> 2;
    const int rp = (rounds + 3) & ~3;  // pad to x4; pad slots are (0,0)
    for (int t = 0; t < rp; t += 4) {
      uint4 rbuf[4];
      float wbuf[4];
#pragma unroll
      for (int r = 0; r < 4; r++) {
        int2 e = sEdge[wv][(t + r) * 4 + slot];
        wbuf[r] = __int_as_float(e.y);
        rbuf[r] = *(const uint4*)((const char*)xwb + (((unsigned)e.x << 8) | (fl << 4)));
      }
#pragma unroll
      for (int r = 0; r < 4; r++) {
        const float w = wbuf[r];
        const uint4 rr = rbuf[r];
        acc[0] += w * bflo(rr.x); acc[1] += w * bfhi(rr.x);
        acc[2] += w * bflo(rr.y); acc[3] += w * bfhi(rr.y);
        acc[4] += w * bflo(rr.z); acc[5] += w * bfhi(rr.z);
        acc[6] += w * bflo(rr.w); acc[7] += w * bfhi(rr.w);
      }
    }
  }

#pragma unroll
  for (int d = 16; d < 64; d <<= 1)
#pragma unroll
    for (int k = 0; k < 8; k++) acc[k] += __shfl_xor(acc[k], d, 64);

  if (slot == 0) {
    float4 b0 = ((const float4*)bias)[fl * 2];
    float4 b1 = ((const float4*)bias)[fl * 2 + 1];
    float a0 = fmaxf(acc[0] + b0.x, 0.f), a1 = fmaxf(acc[1] + b0.y, 0.f);
    float a2 = fmaxf(acc[2] + b0.z, 0.f), a3 = fmaxf(acc[3] + b0.w, 0.f);
    float a4 = fmaxf(acc[4] + b1.x, 0.f), a5 = fmaxf(acc[5] + b1.y, 0.f);
    float a6 = fmaxf(acc[6] + b1.z, 0.f), a7 = fmaxf(acc[7] + b1.w, 0.f);
    uint4 st;
    st.x = (unsigned)f2bf(a0) | ((unsigned)f2bf(a1) << 16);
    st.y = (unsigned)f2bf(a2) | ((unsigned)f2bf(a3) << 16);
    st.z = (unsigned)f2bf(a4) | ((unsigned)f2bf(a5) << 16);
    st.w = (unsigned)f2bf(a6) | ((unsigned)f2bf(a7) << 16);
    *(uint4*)((char*)out + (((size_t)v << 8) | (fl << 4))) = st;
  }
}

// standalone GEMM2 (h1b bf16 -> xw2b bf16)
__global__ __launch_bounds__(256) void k_gemm2(const unsigned short* __restrict__ A,
                                               const float* __restrict__ W,
                                               unsigned short* __restrict__ Y, int N) {
  __shared__ unsigned short Wl[64 * 136];
  gemm_body<64, false>(A, W, Y, N, blockIdx.x, threadIdx.x, Wl);
}

// ---------------- layer-2 aggregate fused with mean-pool accumulation ----------------
__global__ __launch_bounds__(256) void k_aggpool(const unsigned short* __restrict__ xwb,
                                                 const float* __restrict__ dinv,
                                                 const int* __restrict__ start,
                                                 const int* __restrict__ cnt,
                                                 const int2* __restrict__ colw,
                                                 const int* __restrict__ batch,
                                                 float* __restrict__ stage, int N) {
  __shared__ int2 sEdge[4][64];
  __shared__ float sAcc[4][64];
  const int tid = threadIdx.x;
  const int lane = tid & 63;
  const int wv = tid >> 6;
  const int slot = lane >> 3;  // 8 edges per round
  const int fl = lane & 7;     // 16B feature group within 128B row
  const int v = blockIdx.x * 4 + wv;

  float acc[8] = {0.f, 0.f, 0.f, 0.f, 0.f, 0.f, 0.f, 0.f};
  int b = 0;
  if (v < N) {
    b = batch[v];
    const float dv = dinv[v];
    const float d2 = dv * dv;
    if (slot == 0) {
      uint4 s = *(const uint4*)((const char*)xwb + (((size_t)v << 7) | (fl << 4)));
      acc[0] += d2 * bflo(s.x); acc[1] += d2 * bfhi(s.x);
      acc[2] += d2 * bflo(s.y); acc[3] += d2 * bfhi(s.y);
      acc[4] += d2 * bflo(s.z); acc[5] += d2 * bfhi(s.z);
      acc[6] += d2 * bflo(s.w); acc[7] += d2 * bfhi(s.w);
    }
    const int j0 = start[v], jc = cnt[v];
    for (int base = 0; base < jc; base += 64) {
      int2 cw = (base + lane < jc) ? colw[j0 + base + lane] : make_int2(0, 0);
      sEdge[wv][lane] = cw;
      int m = jc - base;
      if (m > 64) m = 64;
      const int rounds = (m + 7) >> 3;       // 1..8
      const int rp = (rounds + 3) & ~3;      // pad to x4
      for (int t = 0; t < rp; t += 4) {
        uint4 rbuf[4];
        float wbuf[4];
#pragma unroll
        for (int r = 0; r < 4; r++) {
          int2 e = sEdge[wv][(t + r) * 8 + slot];
          wbuf[r] = __int_as_float(e.y);
          rbuf[r] = *(const uint4*)((const char*)xwb + (((unsigned)e.x << 7) | (fl << 4)));
        }
#pragma unroll
        for (int r = 0; r < 4; r++) {
          const float w = wbuf[r];
          const uint4 rr = rbuf[r];
          acc[0] += w * bflo(rr.x); acc[1] += w * bfhi(rr.x);
          acc[2] += w * bflo(rr.y); acc[3] += w * bfhi(rr.y);
          acc[4] += w * bflo(rr.z); acc[5] += w * bfhi(rr.z);
          acc[6] += w * bflo(rr.w); acc[7] += w * bfhi(rr.w);
        }
      }
    }
#pragma unroll
    for (int d = 8; d < 64; d <<= 1)
#pragma unroll
      for (int k = 0; k < 8; k++) acc[k] += __shfl_xor(acc[k], d, 64);
  }

  if (slot == 0) {
    *(float4*)&sAcc[wv][fl * 8] = make_float4(acc[0], acc[1], acc[2], acc[3]);
    *(float4*)&sAcc[wv][fl * 8 + 4] = make_float4(acc[4], acc[5], acc[6], acc[7]);
  }
  __syncthreads();

  const int v0 = blockIdx.x * 4;
  const int b0 = batch[min(v0, N - 1)];
  const int b3 = batch[min(v0 + 3, N - 1)];
  if ((b0 == b3) && (v0 + 3 < N)) {  // sorted batch -> block-uniform graph
    if (wv == 0) {
      float t = sAcc[0][lane] + sAcc[1][lane] + sAcc[2][lane] + sAcc[3][lane];
      atomicAdd(&stage[b0 * 64 + lane], t);
    }
  } else if (v < N) {
    atomicAdd(&stage[b * 64 + lane], sAcc[wv][lane]);
  }
}

// counts from sorted-batch first indices (suffix-min), then divide + bias, write d_out
__global__ void k_final(const float* __restrict__ stage, const int* __restrict__ firstIdx,
                        const float* __restrict__ b2, float* __restrict__ out, int N) {
  __shared__ float denom[64];
  const int tid = threadIdx.x;
  if (tid < 64) {
    int raw = firstIdx[tid];
    int fi = (raw > 0) ? raw - 1 : 0x7FFFFFFF;
    int m = fi;
#pragma unroll
    for (int d = 1; d < 64; d <<= 1) {
      int t = __shfl_down(m, d, 64);
      if (tid + d < 64) m = min(m, t);
    }
    int nxtm = __shfl_down(m, 1, 64);          // min first over graphs > tid
    int nxt = (tid == 63) ? N : min(nxtm, N);
    int c = (fi == 0x7FFFFFFF) ? 0 : (nxt - fi);
    denom[tid] = fmaxf((float)c, 1.0f);
  }
  __syncthreads();
  for (int i = tid; i < 64 * 64; i += 256)
    out[i] = stage[i] / denom[i >> 6] + b2[i & 63];
}

// ---------------- launch ----------------

extern "C" void kernel_launch(void* const* d_in, const int* in_sizes, int n_in,
                              void* d_out, int out_size, void* d_ws, size_t ws_size,
                              hipStream_t stream) {
  const float* x     = (const float*)d_in[0];
  const int*   ei    = (const int*)d_in[1];
  const int*   batch = (const int*)d_in[2];
  const float* W1    = (const float*)d_in[3];
  const float* b1    = (const float*)d_in[4];
  const float* W2    = (const float*)d_in[5];
  const float* b2    = (const float*)d_in[6];

  const int N = in_sizes[2];       // 50000
  const int E = in_sizes[1] / 2;   // 800000
  const int* src  = ei;
  const int* dstv = ei + E;

  // workspace layout
  unsigned short* xw1b = (unsigned short*)d_ws;      // N*128 bf16 (xw2b overlays later)
  unsigned short* h1b  = xw1b + (size_t)N * 128;     // N*128 bf16
  unsigned short* xw2b = xw1b;                       // N*64 bf16
  // zero region (single memset): cnt[N], counter[1], firstIdx[64], stage[4096]
  int*   cnt     = (int*)(h1b + (size_t)N * 128);
  int*   counter = cnt + N;
  int*   firstIdx= counter + 1;
  float* stage   = (float*)(firstIdx + 64);          // 64*64
  // non-zeroed scratch
  int*   startv  = (int*)(stage + 4096);             // N
  float* dinv    = (float*)(startv + N);             // N
  int2*  colw    = (int2*)(((uintptr_t)(dinv + N) + 15) & ~(uintptr_t)15);  // E pairs
  int*   rank    = (int*)(colw + E);                 // E (16B-aligned)
  float* outp    = (float*)d_out;                    // 64*64

  hipMemsetAsync(cnt, 0, (size_t)(N + 1 + 64 + 4096) * sizeof(int), stream);

  const int gM  = (N + 63) / 64;      // 782
  const int gE4 = (E + 1023) / 1024;  // 782  (4 edges/thread histogram)
  const int gE  = (E + 255) / 256;    // 3125
  const int gN  = (N + 255) / 256;    // 196
  const int gA  = (N + 3) / 4;        // 12500

  // GEMM1 + histogram/rank + batch boundaries in one launch (independent work)
  k_mega1<<<gM + gE4 + gN, 256, 0, stream>>>(x, W1, xw1b, N, dstv, cnt, rank, E,
                                             batch, firstIdx, gM, gE4);
  k_seg<<<gN, 256, 0, stream>>>(cnt, startv, dinv, counter, N);
  k_fill<<<gE, 256, 0, stream>>>(src, dstv, rank, startv, dinv, colw, E);

  // layer 1 aggregate (+bias+relu)
  k_agg128<<<gA, 256, 0, stream>>>(xw1b, dinv, startv, cnt, colw, b1, h1b, N);

  // layer 2: GEMM then aggregate fused with pooling
  k_gemm2<<<gM, 256, 0, stream>>>(h1b, W2, xw2b, N);
  k_aggpool<<<gA, 256, 0, stream>>>(xw2b, dinv, startv, cnt, colw, batch, stage, N);

  k_final<<<1, 256, 0, stream>>>(stage, firstIdx, b2, outp, N);
}

// Round 6
// 214.407 us; speedup vs baseline: 5.0608x; 1.0868x over previous
//
#include <hip/hip_runtime.h>

typedef __attribute__((ext_vector_type(8))) short bf16x8;
typedef __attribute__((ext_vector_type(4))) float f32x4;

__device__ __forceinline__ unsigned short f2bf(float f) {  // RNE
  unsigned u = __float_as_uint(f);
  u += 0x7FFFu + ((u >> 16) & 1u);
  return (unsigned short)(u >> 16);
}
__device__ __forceinline__ float bflo(unsigned u) { return __uint_as_float(u << 16); }
__device__ __forceinline__ float bfhi(unsigned u) { return __uint_as_float(u & 0xFFFF0000u); }

// ---------------- MFMA bf16 GEMM body (m89/m91-verified layouts) ----------------
template <int CO, bool AF32>
__device__ __forceinline__ void gemm_body(const void* __restrict__ Aptr,
                                          const float* __restrict__ W,
                                          unsigned short* __restrict__ Y, int N,
                                          int bid, int tid, unsigned short* Wl) {
  constexpr int K = 128;
  constexpr int SP = K + 8;  // padded LDS row stride (shorts)
  for (int i = tid; i < K * CO; i += 256) {
    int k = i / CO, n = i % CO;
    Wl[n * SP + k] = f2bf(W[i]);
  }
  __syncthreads();

  const int lane = tid & 63;
  const int quad = lane >> 4, l16 = lane & 15;
  const int mbase = bid * 64 + (tid >> 6) * 16;
  const int arow = min(mbase + l16, N - 1);

  bf16x8 afrag[4];
  if constexpr (AF32) {
    const float* A = (const float*)Aptr + (size_t)arow * K;
#pragma unroll
    for (int ks = 0; ks < 4; ks++) {
      const float4* p = (const float4*)(A + ks * 32 + quad * 8);
      float4 f0 = p[0], f1 = p[1];
      afrag[ks] = (bf16x8){(short)f2bf(f0.x), (short)f2bf(f0.y), (short)f2bf(f0.z), (short)f2bf(f0.w),
                           (short)f2bf(f1.x), (short)f2bf(f1.y), (short)f2bf(f1.z), (short)f2bf(f1.w)};
    }
  } else {
    const unsigned short* A = (const unsigned short*)Aptr + (size_t)arow * K;
#pragma unroll
    for (int ks = 0; ks < 4; ks++) afrag[ks] = *(const bf16x8*)(A + ks * 32 + quad * 8);
  }

#pragma unroll
  for (int ct = 0; ct < CO / 16; ct++) {
    f32x4 acc = {0.0f, 0.0f, 0.0f, 0.0f};
#pragma unroll
    for (int ks = 0; ks < 4; ks++) {
      bf16x8 b = *(const bf16x8*)(&Wl[(ct * 16 + l16) * SP + ks * 32 + quad * 8]);
      acc = __builtin_amdgcn_mfma_f32_16x16x32_bf16(afrag[ks], b, acc, 0, 0, 0);
    }
#pragma unroll
    for (int reg = 0; reg < 4; reg++) {
      int node = mbase + quad * 4 + reg;
      if (node < N) Y[(size_t)node * CO + ct * 16 + l16] = f2bf(acc[reg]);
    }
  }
}

// ---------------- mega1: GEMM1 | edge histogram+rank capture | batch boundaries ----
__global__ __launch_bounds__(256) void k_mega1(const float* __restrict__ x,
                                               const float* __restrict__ W1,
                                               unsigned short* __restrict__ xw1b, int N,
                                               const int* __restrict__ dst,
                                               int* __restrict__ cnt,
                                               int* __restrict__ rank, int E,
                                               const int* __restrict__ batch,
                                               int* __restrict__ firstIdx,
                                               int gM, int gE4) {
  __shared__ unsigned short Wl[128 * 136];
  const int bid = blockIdx.x, tid = threadIdx.x;
  if (bid < gM) {
    gemm_body<128, true>(x, W1, xw1b, N, bid, tid, Wl);
  } else if (bid < gM + gE4) {
    int e0 = (bid - gM) * 1024 + tid * 4;
    if (e0 + 3 < E) {
      int4 d4 = *(const int4*)(dst + e0);
      int4 r;
      r.x = atomicAdd(&cnt[d4.x], 1);
      r.y = atomicAdd(&cnt[d4.y], 1);
      r.z = atomicAdd(&cnt[d4.z], 1);
      r.w = atomicAdd(&cnt[d4.w], 1);
      *(int4*)(rank + e0) = r;
    } else {
      for (int e = e0; e < E; e++) rank[e] = atomicAdd(&cnt[dst[e]], 1);
    }
  } else {
    int n = (bid - gM - gE4) * 256 + tid;
    if (n < N) {
      int b = batch[n];
      if (n == 0 || batch[n - 1] != b) firstIdx[b] = n + 1;  // first occurrence, +1-encoded
    }
  }
}

// ---------------- segment allocation (order-free prefix) ----------------
__global__ void k_seg(const int* __restrict__ cnt, int* __restrict__ start,
                      float* __restrict__ dinv, int* __restrict__ counter, int N) {
  const int v = blockIdx.x * 256 + threadIdx.x;
  const int lane = threadIdx.x & 63;
  int c = (v < N) ? cnt[v] : 0;
  int incl = c;
#pragma unroll
  for (int d = 1; d < 64; d <<= 1) {
    int t = __shfl_up(incl, d, 64);
    if (lane >= d) incl += t;
  }
  int base = 0;
  if (lane == 63) base = atomicAdd(counter, incl);
  base = __shfl(base, 63, 64);
  if (v < N) {
    start[v] = base + incl - c;
    dinv[v] = rsqrtf((float)(c + 1));  // +1 self-loop
  }
}

// atomic-free fill: position = start[dst] + rank[e]
__global__ void k_fill(const int* __restrict__ src, const int* __restrict__ dst,
                       const int* __restrict__ rank, const int* __restrict__ start,
                       const float* __restrict__ dinv, int2* __restrict__ colw, int E) {
  int e = blockIdx.x * 256 + threadIdx.x;
  if (e < E) {
    int s = src[e], d = dst[e];
    int p = start[d] + rank[e];
    float w = dinv[s] * dinv[d];
    colw[p] = make_int2(s, __float_as_int(w));
  }
}

// ---------------- layer-1 aggregate: one vertex per 16-lane group ----------------
// Row = 128 bf16 = 256 B = 16 lanes x 16 B. 4 vertices/wave, 16/block.
// Edge chunk (16) preloaded one-per-lane, broadcast by in-group shfl; 4 loads in flight.
__global__ __launch_bounds__(256) void k_agg128(const unsigned short* __restrict__ xwb,
                                                const float* __restrict__ dinv,
                                                const int* __restrict__ start,
                                                const int* __restrict__ cnt,
                                                const int2* __restrict__ colw,
                                                const float* __restrict__ bias,
                                                unsigned short* __restrict__ out, int N) {
  const int tid = threadIdx.x;
  const int lane = tid & 63;
  const int gl = lane & 15;   // lane within group (16B feature slice)
  const int grp = lane >> 4;  // group within wave (0..3)
  const int wv = tid >> 6;
  const int v = blockIdx.x * 16 + wv * 4 + grp;
  const int vc = min(v, N - 1);

  const float dv = dinv[vc];
  const int j0 = start[vc];
  const int jc = (v < N) ? cnt[vc] : 0;

  // self-loop (each lane owns a distinct 16B slice)
  float acc[8];
  {
    const float d2 = dv * dv;
    uint4 s = *(const uint4*)((const char*)xwb + (((size_t)vc << 8) | (gl << 4)));
    acc[0] = d2 * bflo(s.x); acc[1] = d2 * bfhi(s.x);
    acc[2] = d2 * bflo(s.y); acc[3] = d2 * bfhi(s.y);
    acc[4] = d2 * bflo(s.z); acc[5] = d2 * bfhi(s.z);
    acc[6] = d2 * bflo(s.w); acc[7] = d2 * bfhi(s.w);
  }

  const int gbase = grp << 4;
  for (int base = 0; __any(base < jc); base += 16) {
    int2 cw = (base + gl < jc) ? colw[j0 + base + gl] : make_int2(0, 0);
    int mv = jc - base;
    mv = mv < 0 ? 0 : (mv > 16 ? 16 : mv);
    int mm = max(mv, __shfl_xor(mv, 16, 64));
    mm = max(mm, __shfl_xor(mm, 32, 64));
    const int rp = (mm + 3) & ~3;
    for (int t = 0; t < rp; t += 4) {
      uint4 rbuf[4];
      float wbuf[4];
#pragma unroll
      for (int r = 0; r < 4; r++) {
        int sx = __shfl(cw.x, gbase + t + r, 64);
        wbuf[r] = __int_as_float(__shfl(cw.y, gbase + t + r, 64));
        rbuf[r] = *(const uint4*)((const char*)xwb + (((unsigned)sx << 8) | (gl << 4)));
      }
#pragma unroll
      for (int r = 0; r < 4; r++) {
        const float w = wbuf[r];
        const uint4 rr = rbuf[r];
        acc[0] += w * bflo(rr.x); acc[1] += w * bfhi(rr.x);
        acc[2] += w * bflo(rr.y); acc[3] += w * bfhi(rr.y);
        acc[4] += w * bflo(rr.z); acc[5] += w * bfhi(rr.z);
        acc[6] += w * bflo(rr.w); acc[7] += w * bfhi(rr.w);
      }
    }
  }

  if (v < N) {
    float4 b0 = ((const float4*)bias)[gl * 2];
    float4 b1 = ((const float4*)bias)[gl * 2 + 1];
    float a0 = fmaxf(acc[0] + b0.x, 0.f), a1 = fmaxf(acc[1] + b0.y, 0.f);
    float a2 = fmaxf(acc[2] + b0.z, 0.f), a3 = fmaxf(acc[3] + b0.w, 0.f);
    float a4 = fmaxf(acc[4] + b1.x, 0.f), a5 = fmaxf(acc[5] + b1.y, 0.f);
    float a6 = fmaxf(acc[6] + b1.z, 0.f), a7 = fmaxf(acc[7] + b1.w, 0.f);
    uint4 st;
    st.x = (unsigned)f2bf(a0) | ((unsigned)f2bf(a1) << 16);
    st.y = (unsigned)f2bf(a2) | ((unsigned)f2bf(a3) << 16);
    st.z = (unsigned)f2bf(a4) | ((unsigned)f2bf(a5) << 16);
    st.w = (unsigned)f2bf(a6) | ((unsigned)f2bf(a7) << 16);
    *(uint4*)((char*)out + (((size_t)v << 8) | (gl << 4))) = st;
  }
}

// standalone GEMM2 (h1b bf16 -> xw2b bf16)
__global__ __launch_bounds__(256) void k_gemm2(const unsigned short* __restrict__ A,
                                               const float* __restrict__ W,
                                               unsigned short* __restrict__ Y, int N) {
  __shared__ unsigned short Wl[64 * 136];
  gemm_body<64, false>(A, W, Y, N, blockIdx.x, threadIdx.x, Wl);
}

// ---------------- layer-2 aggregate + mean-pool: one vertex per 8-lane group ------
// Row = 64 bf16 = 128 B = 8 lanes x 16 B. 8 vertices/wave, 32/block.
__global__ __launch_bounds__(256) void k_aggpool(const unsigned short* __restrict__ xwb,
                                                 const float* __restrict__ dinv,
                                                 const int* __restrict__ start,
                                                 const int* __restrict__ cnt,
                                                 const int2* __restrict__ colw,
                                                 const int* __restrict__ batch,
                                                 float* __restrict__ stage, int N) {
  __shared__ float sAcc[4][64];
  const int tid = threadIdx.x;
  const int lane = tid & 63;
  const int gl = lane & 7;    // lane within group (16B slice = 8 feats)
  const int grp = lane >> 3;  // group within wave (0..7)
  const int wv = tid >> 6;
  const int v = blockIdx.x * 32 + wv * 8 + grp;
  const int vc = min(v, N - 1);

  const float dv = dinv[vc];
  const int j0 = start[vc];
  const int jc = (v < N) ? cnt[vc] : 0;
  const int b = batch[vc];

  float acc[8];
  {
    const float d2 = (v < N) ? dv * dv : 0.0f;
    uint4 s = *(const uint4*)((const char*)xwb + (((size_t)vc << 7) | (gl << 4)));
    acc[0] = d2 * bflo(s.x); acc[1] = d2 * bfhi(s.x);
    acc[2] = d2 * bflo(s.y); acc[3] = d2 * bfhi(s.y);
    acc[4] = d2 * bflo(s.z); acc[5] = d2 * bfhi(s.z);
    acc[6] = d2 * bflo(s.w); acc[7] = d2 * bfhi(s.w);
  }

  const int gbase = grp << 3;
  for (int base = 0; __any(base < jc); base += 8) {
    int2 cw = (base + gl < jc) ? colw[j0 + base + gl] : make_int2(0, 0);
    int mv = jc - base;
    mv = mv < 0 ? 0 : (mv > 8 ? 8 : mv);
    int mm = max(mv, __shfl_xor(mv, 8, 64));
    mm = max(mm, __shfl_xor(mm, 16, 64));
    mm = max(mm, __shfl_xor(mm, 32, 64));
    const int rp = (mm + 3) & ~3;
    for (int t = 0; t < rp; t += 4) {
      uint4 rbuf[4];
      float wbuf[4];
#pragma unroll
      for (int r = 0; r < 4; r++) {
        int sx = __shfl(cw.x, gbase + t + r, 64);
        wbuf[r] = __int_as_float(__shfl(cw.y, gbase + t + r, 64));
        rbuf[r] = *(const uint4*)((const char*)xwb + (((unsigned)sx << 7) | (gl << 4)));
      }
#pragma unroll
      for (int r = 0; r < 4; r++) {
        const float w = wbuf[r];
        const uint4 rr = rbuf[r];
        acc[0] += w * bflo(rr.x); acc[1] += w * bfhi(rr.x);
        acc[2] += w * bflo(rr.y); acc[3] += w * bfhi(rr.y);
        acc[4] += w * bflo(rr.z); acc[5] += w * bfhi(rr.z);
        acc[6] += w * bflo(rr.w); acc[7] += w * bfhi(rr.w);
      }
    }
  }

  const int v0 = blockIdx.x * 32;
  const bool uniform = (v0 + 31 < N) && (batch[v0] == batch[v0 + 31]);
  if (uniform) {
    // sum across the 8 groups (feature slice gl preserved)
#pragma unroll
    for (int d = 8; d < 64; d <<= 1)
#pragma unroll
      for (int k = 0; k < 8; k++) acc[k] += __shfl_xor(acc[k], d, 64);
    if (grp == 0) {
      *(float4*)&sAcc[wv][gl * 8] = make_float4(acc[0], acc[1], acc[2], acc[3]);
      *(float4*)&sAcc[wv][gl * 8 + 4] = make_float4(acc[4], acc[5], acc[6], acc[7]);
    }
    __syncthreads();
    if (wv == 0) {
      float t = sAcc[0][lane] + sAcc[1][lane] + sAcc[2][lane] + sAcc[3][lane];
      atomicAdd(&stage[batch[v0] * 64 + lane], t);
    }
  } else if (v < N) {
#pragma unroll
    for (int k = 0; k < 8; k++) atomicAdd(&stage[b * 64 + gl * 8 + k], acc[k]);
  }
}

// counts from sorted-batch first indices (suffix-min), then divide + bias, write d_out
__global__ void k_final(const float* __restrict__ stage, const int* __restrict__ firstIdx,
                        const float* __restrict__ b2, float* __restrict__ out, int N) {
  __shared__ float denom[64];
  const int tid = threadIdx.x;
  if (tid < 64) {
    int raw = firstIdx[tid];
    int fi = (raw > 0) ? raw - 1 : 0x7FFFFFFF;
    int m = fi;
#pragma unroll
    for (int d = 1; d < 64; d <<= 1) {
      int t = __shfl_down(m, d, 64);
      if (tid + d < 64) m = min(m, t);
    }
    int nxtm = __shfl_down(m, 1, 64);          // min first over graphs > tid
    int nxt = (tid == 63) ? N : min(nxtm, N);
    int c = (fi == 0x7FFFFFFF) ? 0 : (nxt - fi);
    denom[tid] = fmaxf((float)c, 1.0f);
  }
  __syncthreads();
  for (int i = tid; i < 64 * 64; i += 256)
    out[i] = stage[i] / denom[i >> 6] + b2[i & 63];
}

// ---------------- launch ----------------

extern "C" void kernel_launch(void* const* d_in, const int* in_sizes, int n_in,
                              void* d_out, int out_size, void* d_ws, size_t ws_size,
                              hipStream_t stream) {
  const float* x     = (const float*)d_in[0];
  const int*   ei    = (const int*)d_in[1];
  const int*   batch = (const int*)d_in[2];
  const float* W1    = (const float*)d_in[3];
  const float* b1    = (const float*)d_in[4];
  const float* W2    = (const float*)d_in[5];
  const float* b2    = (const float*)d_in[6];

  const int N = in_sizes[2];       // 50000
  const int E = in_sizes[1] / 2;   // 800000
  const int* src  = ei;
  const int* dstv = ei + E;

  // workspace layout
  unsigned short* xw1b = (unsigned short*)d_ws;      // N*128 bf16 (xw2b overlays later)
  unsigned short* h1b  = xw1b + (size_t)N * 128;     // N*128 bf16
  unsigned short* xw2b = xw1b;                       // N*64 bf16
  // zero region (single memset): cnt[N], counter[1], firstIdx[64], stage[4096]
  int*   cnt     = (int*)(h1b + (size_t)N * 128);
  int*   counter = cnt + N;
  int*   firstIdx= counter + 1;
  float* stage   = (float*)(firstIdx + 64);          // 64*64
  // non-zeroed scratch
  int*   startv  = (int*)(stage + 4096);             // N
  float* dinv    = (float*)(startv + N);             // N
  int2*  colw    = (int2*)(((uintptr_t)(dinv + N) + 15) & ~(uintptr_t)15);  // E pairs
  int*   rank    = (int*)(colw + E);                 // E (16B-aligned)
  float* outp    = (float*)d_out;                    // 64*64

  hipMemsetAsync(cnt, 0, (size_t)(N + 1 + 64 + 4096) * sizeof(int), stream);

  const int gM  = (N + 63) / 64;      // 782
  const int gE4 = (E + 1023) / 1024;  // 782  (4 edges/thread histogram)
  const int gE  = (E + 255) / 256;    // 3125
  const int gN  = (N + 255) / 256;    // 196
  const int gA1 = (N + 15) / 16;      // 3125 (16 vertices/block)
  const int gA2 = (N + 31) / 32;      // 1563 (32 vertices/block)

  // GEMM1 + histogram/rank + batch boundaries in one launch (independent work)
  k_mega1<<<gM + gE4 + gN, 256, 0, stream>>>(x, W1, xw1b, N, dstv, cnt, rank, E,
                                             batch, firstIdx, gM, gE4);
  k_seg<<<gN, 256, 0, stream>>>(cnt, startv, dinv, counter, N);
  k_fill<<<gE, 256, 0, stream>>>(src, dstv, rank, startv, dinv, colw, E);

  // layer 1 aggregate (+bias+relu)
  k_agg128<<<gA1, 256, 0, stream>>>(xw1b, dinv, startv, cnt, colw, b1, h1b, N);

  // layer 2: GEMM then aggregate fused with pooling
  k_gemm2<<<gM, 256, 0, stream>>>(h1b, W2, xw2b, N);
  k_aggpool<<<gA2, 256, 0, stream>>>(xw2b, dinv, startv, cnt, colw, batch, stage, N);

  k_final<<<1, 256, 0, stream>>>(stage, firstIdx, b2, outp, N);
}